// Round 8
// baseline (147.112 us; speedup 1.0000x reference)
//
#include <hip/hip_runtime.h>
#include <hip/hip_bf16.h>

#define HH 8
#define NNq 2048
#define EPSF 1e-5f
#define LOG2E 1.4426950408889634f

typedef __bf16 bf16x8 __attribute__((ext_vector_type(8)));
typedef float f32x4 __attribute__((ext_vector_type(4)));
typedef float f32x16 __attribute__((ext_vector_type(16)));

typedef const __attribute__((address_space(1))) unsigned int* gas_t;
typedef __attribute__((address_space(3))) unsigned int* las_t;

__device__ __forceinline__ void async16(const void* g, void* l) {
  __builtin_amdgcn_global_load_lds((gas_t)g, (las_t)l, 16, 0, 0);
}
__device__ __forceinline__ void async4(const void* g, void* l) {
  __builtin_amdgcn_global_load_lds((gas_t)g, (las_t)l, 4, 0, 0);
}

__device__ __forceinline__ unsigned short f2bf(float f) {
  union { float f; unsigned int u; } a;
  a.f = f;
  unsigned int r = a.u + 0x7fffu + ((a.u >> 16) & 1u);
  return (unsigned short)(r >> 16);
}

// Chunk-XOR swizzle for bank-conflict-free ds_read_b128 fragments.
__device__ __forceinline__ int swzk(int row, int k) {
  return (k & ~63) | ((((k >> 3) ^ row) & 7) << 3) | (k & 7);
}

// ---------------------------------------------------------------------------
// prep: blocks [0,1024) convert z fp32->bf16 (swizzled); [1024,1280) transpose
// weights fp32->bf16 [n][k] (swizzled); block 1280 zeroes k2max.
// ---------------------------------------------------------------------------
__global__ __launch_bounds__(256) void prep_kernel(
    const float* __restrict__ z, const float* __restrict__ W0,
    const float* __restrict__ W1, const float* __restrict__ W2,
    const float* __restrict__ W3, unsigned short* __restrict__ zb,
    unsigned short* __restrict__ Wt, unsigned int* __restrict__ k2max) {
  __shared__ float Tl[64][68];
  const int t = threadIdx.x;
  const int bx = blockIdx.x;
  if (bx < 1024) {
    const int i = (bx * 256 + t) * 8;
    const int row = i >> 9, k = i & 511;
    const float4 a = *(const float4*)&z[i];
    const float4 b = *(const float4*)&z[i + 4];
    union { unsigned short us[8]; uint4 v; } o;
    o.us[0] = f2bf(a.x); o.us[1] = f2bf(a.y); o.us[2] = f2bf(a.z); o.us[3] = f2bf(a.w);
    o.us[4] = f2bf(b.x); o.us[5] = f2bf(b.y); o.us[6] = f2bf(b.z); o.us[7] = f2bf(b.w);
    *(uint4*)&zb[(row << 9) | swzk(row, k)] = o.v;
  } else if (bx < 1280) {
    const int idx0 = bx - 1024;
    const int wsel = idx0 >> 6, rem = idx0 & 63;
    const int k0 = (rem >> 3) * 64, n0 = (rem & 7) * 64;
    const float* W = (wsel == 0) ? W0 : (wsel == 1) ? W1 : (wsel == 2) ? W2 : W3;
    unsigned short* dst = Wt + (size_t)wsel * 262144;
#pragma unroll
    for (int i = 0; i < 4; ++i) {
      const int idx = t + 256 * i;
      const int row = idx >> 4, cq = (idx & 15) * 4;
      *(float4*)&Tl[row][cq] = *(const float4*)&W[(size_t)(k0 + row) * 512 + n0 + cq];
    }
    __syncthreads();
#pragma unroll
    for (int i = 0; i < 4; ++i) {
      const int idx = t + 256 * i;
      const int nr = idx >> 4, kq = (idx & 15) * 4;
      ushort4 o;
      o.x = f2bf(Tl[kq + 0][nr]);
      o.y = f2bf(Tl[kq + 1][nr]);
      o.z = f2bf(Tl[kq + 2][nr]);
      o.w = f2bf(Tl[kq + 3][nr]);
      const int n = n0 + nr;
      *(ushort4*)&dst[(size_t)n * 512 + swzk(n, k0 + kq)] = o;
    }
  } else {
    k2max[t] = 0u;
  }
}

// ---------------------------------------------------------------------------
// Staged QKV projection + stats (unchanged from R7).
// ---------------------------------------------------------------------------
__global__ __launch_bounds__(256) void gemm_qkv(
    const unsigned short* __restrict__ A, const unsigned short* __restrict__ Wt3,
    const float* __restrict__ bq, const float* __restrict__ bk,
    const float* __restrict__ bvv, unsigned short* __restrict__ Qb,
    unsigned short* __restrict__ Ksw, unsigned short* __restrict__ Vsw,
    float* __restrict__ c1a, float* __restrict__ dva, float* __restrict__ k2a,
    float* __restrict__ q2a, unsigned int* __restrict__ k2max) {
  __shared__ __align__(16) unsigned short S[24576];  // As[128][128] | Bs[64][128]
  __shared__ float wmax[4];

  const int which = blockIdx.z;
  const unsigned short* Wt = Wt3 + (size_t)which * 262144;
  const float* bias = (which == 0) ? bq : (which == 1) ? bk : bvv;

  const int t = threadIdx.x;
  const int w = t >> 6, lane = t & 63, ln = lane & 15, quad = lane >> 4;
  const int r0 = blockIdx.x * 128, h = blockIdx.y;
  const int c0 = h * 64;
  const int b = r0 >> 11, n0 = r0 & 2047;
  const int bh = b * HH + h;

  f32x4 acc[2][4];
#pragma unroll
  for (int rf = 0; rf < 2; ++rf)
#pragma unroll
    for (int nt = 0; nt < 4; ++nt) acc[rf][nt] = (f32x4)(0.0f);

  const int lr = lane >> 4, lc = (lane & 15) * 8;

  for (int k0 = 0; k0 < 512; k0 += 128) {
#pragma unroll
    for (int i = 0; i < 8; ++i)
      async16(A + (size_t)(r0 + w * 32 + i * 4 + lr) * 512 + k0 + lc,
              S + (w * 32 + i * 4) * 128);
#pragma unroll
    for (int i = 0; i < 4; ++i)
      async16(Wt + (size_t)(c0 + w * 16 + i * 4 + lr) * 512 + k0 + lc,
              S + 16384 + (w * 16 + i * 4) * 128);
    __syncthreads();
#pragma unroll
    for (int kk = 0; kk < 128; kk += 32) {
      const int cp = (kk >> 3) + quad;
      const int cs = ((cp & 8) | ((cp ^ (ln & 7)) & 7)) * 8;
      bf16x8 af[2];
#pragma unroll
      for (int rf = 0; rf < 2; ++rf)
        af[rf] = *(const bf16x8*)&S[(w * 32 + rf * 16 + ln) * 128 + cs];
#pragma unroll
      for (int nt = 0; nt < 4; ++nt) {
        const bf16x8 bf = *(const bf16x8*)&S[16384 + (nt * 16 + ln) * 128 + cs];
#pragma unroll
        for (int rf = 0; rf < 2; ++rf)
          acc[rf][nt] = __builtin_amdgcn_mfma_f32_16x16x32_bf16(af[rf], bf, acc[rf][nt], 0, 0, 0);
      }
    }
    __syncthreads();
  }

  float x[2][4][4];
#pragma unroll
  for (int nt = 0; nt < 4; ++nt) {
    const float bv = bias[c0 + nt * 16 + ln];
#pragma unroll
    for (int rf = 0; rf < 2; ++rf)
#pragma unroll
      for (int r = 0; r < 4; ++r) x[rf][nt][r] = acc[rf][nt][r] + bv;
  }

  if (which == 0) {
#pragma unroll
    for (int rf = 0; rf < 2; ++rf)
#pragma unroll
      for (int r = 0; r < 4; ++r) {
        float s1 = x[rf][0][r] + x[rf][1][r] + x[rf][2][r] + x[rf][3][r];
#pragma unroll
        for (int off = 1; off < 16; off <<= 1) s1 += __shfl_xor(s1, off, 64);
        const float mu = s1 * (1.0f / 64.0f);
        float s2 = 0.0f, sa = 0.0f;
#pragma unroll
        for (int nt = 0; nt < 4; ++nt) {
          const float dx = x[rf][nt][r] - mu;
          s2 += dx * dx;
          sa += fabsf(dx);
        }
#pragma unroll
        for (int off = 1; off < 16; off <<= 1) {
          s2 += __shfl_xor(s2, off, 64);
          sa += __shfl_xor(sa, off, 64);
        }
        if (ln == 0) {
          const float sigma = sqrtf(s2 * (1.0f / 64.0f) + EPSF);
          const float nf = sa / (sigma + EPSF);
          const float dInv = 1.0f / (__expf(-nf) + 1.0f);
          const int row = bh * NNq + n0 + w * 32 + rf * 16 + quad * 4 + r;
          c1a[row] = (0.125f + 2.0f * dInv) * LOG2E;
          dva[row] = dInv * LOG2E;
          q2a[row] = s2 + 64.0f * mu * mu;
        }
      }
#pragma unroll
    for (int rf = 0; rf < 2; ++rf)
#pragma unroll
      for (int nt = 0; nt < 4; ++nt)
#pragma unroll
        for (int r = 0; r < 4; ++r)
          S[(w * 32 + rf * 16 + quad * 4 + r) * 72 + nt * 16 + ln] = f2bf(x[rf][nt][r]);
    __syncthreads();
#pragma unroll
    for (int i = 0; i < 4; ++i) {
      const int idx = t + 256 * i;
      const int q = idx >> 3, c = idx & 7;
      *(uint4*)&Qb[((size_t)bh * NNq + n0 + q) * 64 + c * 8] =
          *(const uint4*)&S[q * 72 + c * 8];
    }
  } else if (which == 1) {
    float mx = 0.0f;
#pragma unroll
    for (int rf = 0; rf < 2; ++rf)
#pragma unroll
      for (int r = 0; r < 4; ++r) {
        float s2 = 0.0f;
#pragma unroll
        for (int nt = 0; nt < 4; ++nt) s2 += x[rf][nt][r] * x[rf][nt][r];
#pragma unroll
        for (int off = 1; off < 16; off <<= 1) s2 += __shfl_xor(s2, off, 64);
        if (ln == 0) k2a[bh * NNq + n0 + w * 32 + rf * 16 + quad * 4 + r] = s2;
        mx = fmaxf(mx, s2);
      }
#pragma unroll
    for (int off = 16; off < 64; off <<= 1) mx = fmaxf(mx, __shfl_xor(mx, off, 64));
    if (lane == 0) wmax[w] = mx;
#pragma unroll
    for (int rf = 0; rf < 2; ++rf)
#pragma unroll
      for (int nt = 0; nt < 4; ++nt) {
        const int c = nt * 2 + (ln >> 3);
#pragma unroll
        for (int r = 0; r < 4; ++r) {
          const int key = w * 32 + rf * 16 + quad * 4 + r;
          const int klo = key & 63;
          S[(key >> 6) * 4096 + klo * 64 + ((c ^ (klo & 7)) * 8) + (ln & 7)] =
              f2bf(x[rf][nt][r]);
        }
      }
    __syncthreads();
    if (t == 0) {
      const float m = fmaxf(fmaxf(wmax[0], wmax[1]), fmaxf(wmax[2], wmax[3]));
      atomicMax(&k2max[bh * 16], __float_as_uint(m));
    }
    unsigned short* dst = Ksw + ((size_t)bh * 32 + (n0 >> 6)) * 4096;
#pragma unroll
    for (int i = 0; i < 4; ++i) {
      const int idx = t + 256 * i;
      *(uint4*)&dst[idx * 8] = *(const uint4*)&S[idx * 8];
    }
  } else {
#pragma unroll
    for (int rf = 0; rf < 2; ++rf)
#pragma unroll
      for (int nt = 0; nt < 4; ++nt) {
        const int d = nt * 16 + ln;
#pragma unroll
        for (int r = 0; r < 4; ++r) {
          const int key = w * 32 + rf * 16 + quad * 4 + r;
          const int klo = key & 63;
          S[d * 128 + (key >> 6) * 64 + (((klo >> 3) ^ (d & 7)) * 8) + (klo & 7)] =
              f2bf(x[rf][nt][r]);
        }
      }
    __syncthreads();
    unsigned short* dst = Vsw + ((size_t)bh * 32 + (n0 >> 6)) * 4096;
#pragma unroll
    for (int i = 0; i < 4; ++i) {
      const int g = t + 256 * i;
      const int tile = g >> 9, d = (g >> 3) & 63, j8 = (g & 7) * 8;
      *(uint4*)&dst[tile * 4096 + d * 64 + j8] =
          *(const uint4*)&S[d * 128 + tile * 64 + j8];
    }
  }
}

// ---------------------------------------------------------------------------
// Flash attention v2: 32x32x16 MFMA, grid (32 qt, 16 bh, 4 key-splits),
// 4 waves (qi = wave&1 query group, ki = wave>>1 key subgroup of each tile).
// Wave computes S^T[32k x 32q] (A=K, B=Q regs; lane owns query col lane&31),
// fixed-bound softmax (shared shift Mq -> partials add exactly), wave-private
// P -> PV over its 32 keys, full 64 d (2 C-tiles). fp32 (O,L) partials to
// global; combine kernel merges the 4 key-splits.
// ---------------------------------------------------------------------------
__global__ __launch_bounds__(256) void attn_kernel(
    const unsigned short* __restrict__ Qb, const unsigned short* __restrict__ Ksw,
    const unsigned short* __restrict__ Vsw, const float* __restrict__ c1a,
    const float* __restrict__ dva, const float* __restrict__ k2a,
    const float* __restrict__ q2a, const unsigned int* __restrict__ k2maxu,
    float* __restrict__ Opart, float* __restrict__ Lpart) {
  // [0,8192) Kt | [8192,16384) Vt | [16384,26624) Ps 4x[32][40] | [26624,28672) k2h
  // epilogue: Ost fp32[64][64] aliases Kt+Vt; Lst aliases Ps.
  __shared__ __align__(16) char smem[28672];
  unsigned short* Kt = (unsigned short*)smem;
  unsigned short* Vt = (unsigned short*)(smem + 8192);
  float* k2h = (float*)(smem + 26624);

  const int t = threadIdx.x;
  const int w4 = t >> 6, lane = t & 63, lq = lane & 31, lh = lane >> 5;
  const int qi = w4 & 1, ki = w4 >> 1;
  const int qt = blockIdx.x, bh = blockIdx.y, ks = blockIdx.z;
  const int q0 = qt * 64;
  const int rowbase = bh * NNq;
  const int pb = (qt * 16 + bh) * 4 + ks;

  unsigned short* Ps = (unsigned short*)(smem + 16384 + w4 * 2560);  // [32][40]

  // stage this quarter's k2 (512 floats)
  const float* k2g = k2a + rowbase + ks * 512;
  async4(k2g + (w4 * 2 + 0) * 64 + lane, k2h + (w4 * 2 + 0) * 64);
  async4(k2g + (w4 * 2 + 1) * 64 + lane, k2h + (w4 * 2 + 1) * 64);

  // Q B-frags: query qg; chunk T holds d = T*16 + lh*8 .. +8
  const int qg = q0 + qi * 32 + lq;
  const unsigned short* qrow = Qb + ((size_t)rowbase + qg) * 64;
  bf16x8 bq[4];
#pragma unroll
  for (int T = 0; T < 4; ++T) bq[T] = *(const bf16x8*)(qrow + T * 16 + lh * 8);

  const float k2m = __uint_as_float(k2maxu[bh * 16]);
  const float c1q = c1a[rowbase + qg];
  const float dvq = dva[rowbase + qg];
  const float Mqq = c1q * sqrtf(q2a[rowbase + qg] * k2m);
  float L = 0.0f;
  f32x16 O[2];
  O[0] = (f32x16)(0.0f);
  O[1] = (f32x16)(0.0f);

  const unsigned short* Kg = Ksw + ((size_t)bh * 32 + ks * 8) * 4096;
  const unsigned short* Vg = Vsw + ((size_t)bh * 32 + ks * 8) * 4096;
  const int krow = ki * 32 + lq;  // this wave's K row for A-frags

  for (int kt = 0; kt < 8; ++kt) {
    {
      const size_t tb = (size_t)kt * 4096 + w4 * 1024;
      async16(Kg + tb + lane * 8, Kt + w4 * 1024);
      async16(Kg + tb + 512 + lane * 8, Kt + w4 * 1024 + 512);
      async16(Vg + tb + lane * 8, Vt + w4 * 1024);
      async16(Vg + tb + 512 + lane * 8, Vt + w4 * 1024 + 512);
    }
    __syncthreads();

    // ---- S^T[32k x 32q]: A = K rows (krow), B = Q ----
    f32x16 s = (f32x16)(0.0f);
    const unsigned short* kb = Kt + krow * 64;
#pragma unroll
    for (int T = 0; T < 4; ++T) {
      const int chunk = (T * 2 + lh) ^ (krow & 7);
      const bf16x8 ak = *(const bf16x8*)(kb + chunk * 8);
      s = __builtin_amdgcn_mfma_f32_32x32x16_bf16(ak, bq[T], s, 0, 0, 0);
    }

    // ---- softmax: reg r -> key ki*32 + 4*lh + (r&3) + 8*(r>>2) ----
#pragma unroll
    for (int rq = 0; rq < 4; ++rq) {
      const int kb4 = 4 * lh + 8 * rq;  // key base within the 32-key quadrant
      const f32x4 k2v = *(const f32x4*)&k2h[kt * 64 + ki * 32 + kb4];
      const float p0 = __builtin_amdgcn_exp2f(c1q * s[rq * 4 + 0] - dvq * k2v[0] - Mqq);
      const float p1 = __builtin_amdgcn_exp2f(c1q * s[rq * 4 + 1] - dvq * k2v[1] - Mqq);
      const float p2 = __builtin_amdgcn_exp2f(c1q * s[rq * 4 + 2] - dvq * k2v[2] - Mqq);
      const float p3 = __builtin_amdgcn_exp2f(c1q * s[rq * 4 + 3] - dvq * k2v[3] - Mqq);
      L += (p0 + p1) + (p2 + p3);
      union { __hip_bfloat162 h; unsigned int u; } c01, c23;
      c01.h = __float22bfloat162_rn(make_float2(p0, p1));
      c23.h = __float22bfloat162_rn(make_float2(p2, p3));
      uint2 pu; pu.x = c01.u; pu.y = c23.u;
      *(uint2*)&Ps[lq * 40 + kb4] = pu;  // P^T: row = query lq, 4 consec keys
    }

    // ---- PV: A = own P [32q x 32k], B = V [32k x 64d] (2 d-tiles) ----
    bf16x8 pa[2];
#pragma unroll
    for (int T2 = 0; T2 < 2; ++T2)
      pa[T2] = *(const bf16x8*)&Ps[lq * 40 + T2 * 16 + lh * 8];
#pragma unroll
    for (int dt = 0; dt < 2; ++dt) {
      const int dcol = dt * 32 + lq;
      const unsigned short* vb = Vt + dcol * 64;
#pragma unroll
      for (int T2 = 0; T2 < 2; ++T2) {
        const int chunk = (ki * 4 + T2 * 2 + lh) ^ (dcol & 7);
        const bf16x8 bv = *(const bf16x8*)(vb + chunk * 8);
        O[dt] = __builtin_amdgcn_mfma_f32_32x32x16_bf16(pa[T2], bv, O[dt], 0, 0, 0);
      }
    }
    __syncthreads();
  }

  // L: lanes lq and lq+32 hold disjoint key subsets of the same query.
  L += __shfl_xor(L, 32, 64);

  // ---- in-block merge of the two ki waves; write fp32 partials ----
  float* Ost = (float*)smem;            // [64][64]
  float* Lst = (float*)(smem + 16384);  // [64]
  if (ki == 0) {
#pragma unroll
    for (int dt = 0; dt < 2; ++dt)
#pragma unroll
      for (int r = 0; r < 16; ++r) {
        const int qrow2 = qi * 32 + (r & 3) + 8 * (r >> 2) + 4 * lh;
        Ost[qrow2 * 64 + dt * 32 + lq] = O[dt][r];
      }
    if (lane < 32) Lst[qi * 32 + lq] = L;
  }
  __syncthreads();
  if (ki == 1) {
#pragma unroll
    for (int dt = 0; dt < 2; ++dt)
#pragma unroll
      for (int r = 0; r < 16; ++r) {
        const int qrow2 = qi * 32 + (r & 3) + 8 * (r >> 2) + 4 * lh;
        Ost[qrow2 * 64 + dt * 32 + lq] += O[dt][r];
      }
    if (lane < 32) Lst[qi * 32 + lq] += L;
  }
  __syncthreads();
#pragma unroll
  for (int i = 0; i < 4; ++i) {
    const int f4 = t + i * 256;
    *(float4*)&Opart[(size_t)pb * 4096 + f4 * 4] = *(const float4*)&Ost[f4 * 4];
  }
  if (t < 64) Lpart[pb * 64 + t] = Lst[t];
}

// ---------------------------------------------------------------------------
// Combine the 4 key-split partials; normalize; write swizzled bf16 attnb.
// grid (32 qt, 16 bh), 256 thr: thread = (query q = t>>2, 16-d segment).
// ---------------------------------------------------------------------------
__global__ __launch_bounds__(256) void attn_combine(
    const float* __restrict__ Opart, const float* __restrict__ Lpart,
    unsigned short* __restrict__ attnb) {
  const int t = threadIdx.x;
  const int qt = blockIdx.x, bh = blockIdx.y;
  const int b = bh >> 3, h = bh & 7;
  const int q = t >> 2, dseg = (t & 3) * 16;
  const int pbase = (qt * 16 + bh) * 4;

  float Ls = 0.0f;
#pragma unroll
  for (int ks = 0; ks < 4; ++ks) Ls += Lpart[(pbase + ks) * 64 + q];
  const float inv = 1.0f / Ls;

  float acc[16];
#pragma unroll
  for (int j = 0; j < 16; ++j) acc[j] = 0.0f;
#pragma unroll
  for (int ks = 0; ks < 4; ++ks) {
    const float* src = Opart + (size_t)(pbase + ks) * 4096 + q * 64 + dseg;
#pragma unroll
    for (int i = 0; i < 4; ++i) {
      const float4 v = *(const float4*)&src[i * 4];
      acc[i * 4 + 0] += v.x; acc[i * 4 + 1] += v.y;
      acc[i * 4 + 2] += v.z; acc[i * 4 + 3] += v.w;
    }
  }
  union { unsigned short us[16]; uint4 v[2]; } ov;
#pragma unroll
  for (int j = 0; j < 16; ++j) ov.us[j] = f2bf(acc[j] * inv);
  const int n = qt * 64 + q;
  unsigned short* dst = attnb + ((size_t)(b * NNq + n)) * 512;
  *(uint4*)&dst[swzk(n, h * 64 + dseg)] = ov.v[0];
  *(uint4*)&dst[swzk(n, h * 64 + dseg + 8)] = ov.v[1];
}

// ---------------------------------------------------------------------------
// Staged out projection (unchanged from R7).
// ---------------------------------------------------------------------------
__global__ __launch_bounds__(256) void gemm_out(
    const unsigned short* __restrict__ A, const unsigned short* __restrict__ Wt,
    const float* __restrict__ bias, float* __restrict__ of) {
  __shared__ __align__(16) char sbuf[32768];
  unsigned short* S = (unsigned short*)sbuf;
  float (*Tl)[68] = (float(*)[68])sbuf;

  const int t = threadIdx.x;
  const int w = t >> 6, lane = t & 63, ln = lane & 15, quad = lane >> 4;
  const int r0 = blockIdx.x * 64, c0 = blockIdx.y * 64;
  const int lr = lane >> 4, lc = (lane & 15) * 8;

  f32x4 acc[4];
#pragma unroll
  for (int nt = 0; nt < 4; ++nt) acc[nt] = (f32x4)(0.0f);

  for (int k0 = 0; k0 < 512; k0 += 128) {
#pragma unroll
    for (int i = 0; i < 4; ++i) {
      async16(A + (size_t)(r0 + w * 16 + i * 4 + lr) * 512 + k0 + lc,
              S + (w * 16 + i * 4) * 128);
      async16(Wt + (size_t)(c0 + w * 16 + i * 4 + lr) * 512 + k0 + lc,
              S + 8192 + (w * 16 + i * 4) * 128);
    }
    __syncthreads();
#pragma unroll
    for (int kk = 0; kk < 128; kk += 32) {
      const int cp = (kk >> 3) + quad;
      const int cs = ((cp & 8) | ((cp ^ (ln & 7)) & 7)) * 8;
      const bf16x8 af = *(const bf16x8*)&S[(w * 16 + ln) * 128 + cs];
#pragma unroll
      for (int nt = 0; nt < 4; ++nt) {
        const bf16x8 bf = *(const bf16x8*)&S[8192 + (nt * 16 + ln) * 128 + cs];
        acc[nt] = __builtin_amdgcn_mfma_f32_16x16x32_bf16(af, bf, acc[nt], 0, 0, 0);
      }
    }
    __syncthreads();
  }
#pragma unroll
  for (int nt = 0; nt < 4; ++nt) {
    const float bv = bias[c0 + nt * 16 + ln];
#pragma unroll
    for (int r = 0; r < 4; ++r)
      Tl[w * 16 + quad * 4 + r][nt * 16 + ln] = acc[nt][r] + bv;
  }
  __syncthreads();
#pragma unroll
  for (int i = 0; i < 4; ++i) {
    const int idx = t + 256 * i;
    const int row = idx >> 4, c4 = (idx & 15) * 4;
    *(float4*)&of[(size_t)(r0 + row) * 512 + c0 + c4] = *(const float4*)&Tl[row][c4];
  }
}

// ---------------------------------------------------------------------------
extern "C" void kernel_launch(void* const* d_in, const int* in_sizes, int n_in,
                              void* d_out, int out_size, void* d_ws,
                              size_t ws_size, hipStream_t stream) {
  const float* z = (const float*)d_in[0];
  const float* Wq = (const float*)d_in[1];
  const float* bq = (const float*)d_in[2];
  const float* Wk = (const float*)d_in[3];
  const float* bk = (const float*)d_in[4];
  const float* Wv = (const float*)d_in[5];
  const float* bv = (const float*)d_in[6];
  const float* Wo = (const float*)d_in[7];
  const float* bo = (const float*)d_in[8];
  float* out = (float*)d_out;

  char* ws = (char*)d_ws;
  unsigned short* zb = (unsigned short*)(ws);                // 4 MiB
  unsigned short* Wt = (unsigned short*)(ws + 4194304);      // 2 MiB
  unsigned short* Qb = (unsigned short*)(ws + 6291456);      // 4 MiB
  unsigned short* Ksw = (unsigned short*)(ws + 10485760);    // 4 MiB
  unsigned short* Vsw = (unsigned short*)(ws + 14680064);    // 4 MiB
  float* c1 = (float*)(ws + 18874368);                       // 128 KiB each
  float* dv = (float*)(ws + 19005440);
  float* k2 = (float*)(ws + 19136512);
  float* q2 = (float*)(ws + 19267584);
  unsigned short* attnb = (unsigned short*)(ws + 19398656);  // 4 MiB
  unsigned int* k2max = (unsigned int*)(ws + 23592960);      // 1 KiB
  float* Opart = (float*)(ws + 23593984);                    // 32 MiB
  float* Lpart = (float*)(ws + 57148416);                    // 512 KiB

  hipLaunchKernelGGL(prep_kernel, dim3(1281), dim3(256), 0, stream, z, Wq, Wk,
                     Wv, Wo, zb, Wt, k2max);
  hipLaunchKernelGGL(gemm_qkv, dim3(32, 8, 3), dim3(256), 0, stream, zb, Wt,
                     bq, bk, bv, Qb, Ksw, Vsw, c1, dv, k2, q2, k2max);
  hipLaunchKernelGGL(attn_kernel, dim3(32, 16, 4), dim3(256), 0, stream, Qb,
                     Ksw, Vsw, c1, dv, k2, q2, k2max, Opart, Lpart);
  hipLaunchKernelGGL(attn_combine, dim3(32, 16), dim3(256), 0, stream, Opart,
                     Lpart, attnb);
  hipLaunchKernelGGL(gemm_out, dim3(64, 8), dim3(256), 0, stream, attnb,
                     Wt + 786432, bo, out);
}

// Round 11
// 135.351 us; speedup vs baseline: 1.0869x; 1.0869x over previous
//
#include <hip/hip_runtime.h>
#include <hip/hip_bf16.h>

#define HH 8
#define NNq 2048
#define EPSF 1e-5f
#define LOG2E 1.4426950408889634f

typedef __bf16 bf16x8 __attribute__((ext_vector_type(8)));
typedef float f32x4 __attribute__((ext_vector_type(4)));

typedef const __attribute__((address_space(1))) unsigned int* gas_t;
typedef __attribute__((address_space(3))) unsigned int* las_t;

__device__ __forceinline__ void async16(const void* g, void* l) {
  __builtin_amdgcn_global_load_lds((gas_t)g, (las_t)l, 16, 0, 0);
}
__device__ __forceinline__ void async4(const void* g, void* l) {
  __builtin_amdgcn_global_load_lds((gas_t)g, (las_t)l, 4, 0, 0);
}

__device__ __forceinline__ unsigned short f2bf(float f) {
  union { float f; unsigned int u; } a;
  a.f = f;
  unsigned int r = a.u + 0x7fffu + ((a.u >> 16) & 1u);
  return (unsigned short)(r >> 16);
}

// Chunk-XOR swizzle for bank-conflict-free ds_read_b128 fragments.
// Element (row, k) of a row-major [R x 512] bf16 matrix is stored at
// row*512 + swzk(row, k). 8-element (16B) chunks permute within 64-el groups.
__device__ __forceinline__ int swzk(int row, int k) {
  return (k & ~63) | ((((k >> 3) ^ row) & 7) << 3) | (k & 7);
}

// ---------------------------------------------------------------------------
// prep: blocks [0,1024) convert z fp32->bf16 (swizzled); [1024,1280) transpose
// weights fp32->bf16 [n][k] (swizzled); block 1280 zeroes k2max.
// ---------------------------------------------------------------------------
__global__ __launch_bounds__(256) void prep_kernel(
    const float* __restrict__ z, const float* __restrict__ W0,
    const float* __restrict__ W1, const float* __restrict__ W2,
    const float* __restrict__ W3, unsigned short* __restrict__ zb,
    unsigned short* __restrict__ Wt, unsigned int* __restrict__ k2max) {
  __shared__ float Tl[64][68];
  const int t = threadIdx.x;
  const int bx = blockIdx.x;
  if (bx < 1024) {
    const int i = (bx * 256 + t) * 8;
    const int row = i >> 9, k = i & 511;
    const float4 a = *(const float4*)&z[i];
    const float4 b = *(const float4*)&z[i + 4];
    union { unsigned short us[8]; uint4 v; } o;
    o.us[0] = f2bf(a.x); o.us[1] = f2bf(a.y); o.us[2] = f2bf(a.z); o.us[3] = f2bf(a.w);
    o.us[4] = f2bf(b.x); o.us[5] = f2bf(b.y); o.us[6] = f2bf(b.z); o.us[7] = f2bf(b.w);
    *(uint4*)&zb[(row << 9) | swzk(row, k)] = o.v;
  } else if (bx < 1280) {
    const int idx0 = bx - 1024;
    const int wsel = idx0 >> 6, rem = idx0 & 63;
    const int k0 = (rem >> 3) * 64, n0 = (rem & 7) * 64;
    const float* W = (wsel == 0) ? W0 : (wsel == 1) ? W1 : (wsel == 2) ? W2 : W3;
    unsigned short* dst = Wt + (size_t)wsel * 262144;
#pragma unroll
    for (int i = 0; i < 4; ++i) {
      const int idx = t + 256 * i;
      const int row = idx >> 4, cq = (idx & 15) * 4;
      *(float4*)&Tl[row][cq] = *(const float4*)&W[(size_t)(k0 + row) * 512 + n0 + cq];
    }
    __syncthreads();
#pragma unroll
    for (int i = 0; i < 4; ++i) {
      const int idx = t + 256 * i;
      const int nr = idx >> 4, kq = (idx & 15) * 4;
      ushort4 o;
      o.x = f2bf(Tl[kq + 0][nr]);
      o.y = f2bf(Tl[kq + 1][nr]);
      o.z = f2bf(Tl[kq + 2][nr]);
      o.w = f2bf(Tl[kq + 3][nr]);
      const int n = n0 + nr;
      *(ushort4*)&dst[(size_t)n * 512 + swzk(n, k0 + kq)] = o;
    }
  } else {
    k2max[t] = 0u;
  }
}

// ---------------------------------------------------------------------------
// Staged QKV projection + stats. 128 rows x 64 cols (one head) per block.
// BK=128 (4 K-iters), swizzle-aware conflict-free fragment reads.
// mode 0: Q bf16 [bh][n][64] (linear) + c1/dv/q2. mode 1: K swizzled attn
// tiles + k2/k2max. mode 2: V swizzled attn tiles (rows=dim, cols=key).
// ---------------------------------------------------------------------------
__global__ __launch_bounds__(256) void gemm_qkv(
    const unsigned short* __restrict__ A, const unsigned short* __restrict__ Wt3,
    const float* __restrict__ bq, const float* __restrict__ bk,
    const float* __restrict__ bvv, unsigned short* __restrict__ Qb,
    unsigned short* __restrict__ Ksw, unsigned short* __restrict__ Vsw,
    float* __restrict__ c1a, float* __restrict__ dva, float* __restrict__ k2a,
    float* __restrict__ q2a, unsigned int* __restrict__ k2max) {
  __shared__ __align__(16) unsigned short S[24576];  // As[128][128] | Bs[64][128]
  __shared__ float wmax[4];

  const int which = blockIdx.z;
  const unsigned short* Wt = Wt3 + (size_t)which * 262144;
  const float* bias = (which == 0) ? bq : (which == 1) ? bk : bvv;

  const int t = threadIdx.x;
  const int w = t >> 6, lane = t & 63, ln = lane & 15, quad = lane >> 4;
  const int r0 = blockIdx.x * 128, h = blockIdx.y;
  const int c0 = h * 64;
  const int b = r0 >> 11, n0 = r0 & 2047;
  const int bh = b * HH + h;

  f32x4 acc[2][4];
#pragma unroll
  for (int rf = 0; rf < 2; ++rf)
#pragma unroll
    for (int nt = 0; nt < 4; ++nt) acc[rf][nt] = (f32x4)(0.0f);

  const int lr = lane >> 4, lc = (lane & 15) * 8;  // 16 lanes per 256B row

  for (int k0 = 0; k0 < 512; k0 += 128) {
#pragma unroll
    for (int i = 0; i < 8; ++i)
      async16(A + (size_t)(r0 + w * 32 + i * 4 + lr) * 512 + k0 + lc,
              S + (w * 32 + i * 4) * 128);
#pragma unroll
    for (int i = 0; i < 4; ++i)
      async16(Wt + (size_t)(c0 + w * 16 + i * 4 + lr) * 512 + k0 + lc,
              S + 16384 + (w * 16 + i * 4) * 128);
    __syncthreads();
#pragma unroll
    for (int kk = 0; kk < 128; kk += 32) {
      const int cp = (kk >> 3) + quad;
      const int cs = ((cp & 8) | ((cp ^ (ln & 7)) & 7)) * 8;
      bf16x8 af[2];
#pragma unroll
      for (int rf = 0; rf < 2; ++rf)
        af[rf] = *(const bf16x8*)&S[(w * 32 + rf * 16 + ln) * 128 + cs];
#pragma unroll
      for (int nt = 0; nt < 4; ++nt) {
        const bf16x8 bf = *(const bf16x8*)&S[16384 + (nt * 16 + ln) * 128 + cs];
#pragma unroll
        for (int rf = 0; rf < 2; ++rf)
          acc[rf][nt] = __builtin_amdgcn_mfma_f32_16x16x32_bf16(af[rf], bf, acc[rf][nt], 0, 0, 0);
      }
    }
    __syncthreads();
  }

  float x[2][4][4];  // [rf][nt][r]
#pragma unroll
  for (int nt = 0; nt < 4; ++nt) {
    const float bv = bias[c0 + nt * 16 + ln];
#pragma unroll
    for (int rf = 0; rf < 2; ++rf)
#pragma unroll
      for (int r = 0; r < 4; ++r) x[rf][nt][r] = acc[rf][nt][r] + bv;
  }

  if (which == 0) {
#pragma unroll
    for (int rf = 0; rf < 2; ++rf)
#pragma unroll
      for (int r = 0; r < 4; ++r) {
        float s1 = x[rf][0][r] + x[rf][1][r] + x[rf][2][r] + x[rf][3][r];
#pragma unroll
        for (int off = 1; off < 16; off <<= 1) s1 += __shfl_xor(s1, off, 64);
        const float mu = s1 * (1.0f / 64.0f);
        float s2 = 0.0f, sa = 0.0f;
#pragma unroll
        for (int nt = 0; nt < 4; ++nt) {
          const float dx = x[rf][nt][r] - mu;
          s2 += dx * dx;
          sa += fabsf(dx);
        }
#pragma unroll
        for (int off = 1; off < 16; off <<= 1) {
          s2 += __shfl_xor(s2, off, 64);
          sa += __shfl_xor(sa, off, 64);
        }
        if (ln == 0) {
          const float sigma = sqrtf(s2 * (1.0f / 64.0f) + EPSF);
          const float nf = sa / (sigma + EPSF);
          const float dInv = 1.0f / (__expf(-nf) + 1.0f);
          const int row = bh * NNq + n0 + w * 32 + rf * 16 + quad * 4 + r;
          c1a[row] = (0.125f + 2.0f * dInv) * LOG2E;
          dva[row] = dInv * LOG2E;
          q2a[row] = s2 + 64.0f * mu * mu;
        }
      }
#pragma unroll
    for (int rf = 0; rf < 2; ++rf)
#pragma unroll
      for (int nt = 0; nt < 4; ++nt)
#pragma unroll
        for (int r = 0; r < 4; ++r)
          S[(w * 32 + rf * 16 + quad * 4 + r) * 72 + nt * 16 + ln] = f2bf(x[rf][nt][r]);
    __syncthreads();
#pragma unroll
    for (int i = 0; i < 4; ++i) {
      const int idx = t + 256 * i;
      const int q = idx >> 3, c = idx & 7;
      *(uint4*)&Qb[((size_t)bh * NNq + n0 + q) * 64 + c * 8] =
          *(const uint4*)&S[q * 72 + c * 8];
    }
  } else if (which == 1) {
    float mx = 0.0f;
#pragma unroll
    for (int rf = 0; rf < 2; ++rf)
#pragma unroll
      for (int r = 0; r < 4; ++r) {
        float s2 = 0.0f;
#pragma unroll
        for (int nt = 0; nt < 4; ++nt) s2 += x[rf][nt][r] * x[rf][nt][r];
#pragma unroll
        for (int off = 1; off < 16; off <<= 1) s2 += __shfl_xor(s2, off, 64);
        if (ln == 0) k2a[bh * NNq + n0 + w * 32 + rf * 16 + quad * 4 + r] = s2;
        mx = fmaxf(mx, s2);
      }
#pragma unroll
    for (int off = 16; off < 64; off <<= 1) mx = fmaxf(mx, __shfl_xor(mx, off, 64));
    if (lane == 0) wmax[w] = mx;
#pragma unroll
    for (int rf = 0; rf < 2; ++rf)
#pragma unroll
      for (int nt = 0; nt < 4; ++nt) {
        const int c = nt * 2 + (ln >> 3);
#pragma unroll
        for (int r = 0; r < 4; ++r) {
          const int key = w * 32 + rf * 16 + quad * 4 + r;
          const int klo = key & 63;
          S[(key >> 6) * 4096 + klo * 64 + ((c ^ (klo & 7)) * 8) + (ln & 7)] =
              f2bf(x[rf][nt][r]);
        }
      }
    __syncthreads();
    if (t == 0) {
      const float m = fmaxf(fmaxf(wmax[0], wmax[1]), fmaxf(wmax[2], wmax[3]));
      atomicMax(&k2max[bh * 16], __float_as_uint(m));
    }
    unsigned short* dst = Ksw + ((size_t)bh * 32 + (n0 >> 6)) * 4096;
#pragma unroll
    for (int i = 0; i < 4; ++i) {
      const int idx = t + 256 * i;
      *(uint4*)&dst[idx * 8] = *(const uint4*)&S[idx * 8];
    }
  } else {
#pragma unroll
    for (int rf = 0; rf < 2; ++rf)
#pragma unroll
      for (int nt = 0; nt < 4; ++nt) {
        const int d = nt * 16 + ln;
#pragma unroll
        for (int r = 0; r < 4; ++r) {
          const int key = w * 32 + rf * 16 + quad * 4 + r;
          const int klo = key & 63;
          S[d * 128 + (key >> 6) * 64 + (((klo >> 3) ^ (d & 7)) * 8) + (klo & 7)] =
              f2bf(x[rf][nt][r]);
        }
      }
    __syncthreads();
    unsigned short* dst = Vsw + ((size_t)bh * 32 + (n0 >> 6)) * 4096;
#pragma unroll
    for (int i = 0; i < 4; ++i) {
      const int g = t + 256 * i;
      const int tile = g >> 9, d = (g >> 3) & 63, j8 = (g & 7) * 8;
      *(uint4*)&dst[tile * 4096 + d * 64 + j8] =
          *(const uint4*)&S[d * 128 + tile * 64 + j8];
    }
  }
}

// ---------------------------------------------------------------------------
// Flash attention, 512 threads = 8 waves: waves 0-3 keys [0,1024),
// waves 4-7 keys [1024,2048). Fixed-bound softmax; k2 preloaded per half;
// P packed with native __float22bfloat162_rn; swizzled attnb output.
// ---------------------------------------------------------------------------
__global__ __launch_bounds__(512) void attn_kernel(
    const unsigned short* __restrict__ Qb, const unsigned short* __restrict__ Ksw,
    const unsigned short* __restrict__ Vsw, const float* __restrict__ c1a,
    const float* __restrict__ dva, const float* __restrict__ k2a,
    const float* __restrict__ q2a, const unsigned int* __restrict__ k2maxu,
    unsigned short* __restrict__ attnb) {
  // [0,32768): per-half K(8K)+V(8K); aliased as fp32 O partials at the end.
  // [32768,51200): per-half Ps [64][72] bf16; aliased as L storage.
  // [51200,59392): per-half k2 (1024 floats each).
  __shared__ __align__(16) char smem[59392];

  const int t = threadIdx.x;
  const int w8 = t >> 6, lane = t & 63, ln = lane & 15, quad = lane >> 4;
  const int half = w8 >> 2, wl = w8 & 3;
  const int qt = blockIdx.x, bh = blockIdx.y;
  const int b = bh >> 3, h = bh & 7;
  const int q0 = qt * 64;
  const int rowbase = bh * NNq;

  unsigned short* Kt = (unsigned short*)(smem + half * 16384);
  unsigned short* Vt = (unsigned short*)(smem + half * 16384 + 8192);
  unsigned short* Ps = (unsigned short*)(smem + 32768 + half * 9216);
  float* k2h = (float*)(smem + 51200 + half * 4096);

  // Preload this half's k2 (1024 floats) once.
  const float* k2g = k2a + rowbase + half * 1024;
#pragma unroll
  for (int i = 0; i < 4; ++i)
    async4(k2g + wl * 256 + i * 64 + lane, k2h + wl * 256 + i * 64);

  // Q fragment: lane ln holds query q0 + wl*16 + ln (B-operand for S^T).
  const int qg = q0 + wl * 16 + ln;
  const unsigned short* qrow = Qb + ((size_t)rowbase + qg) * 64;
  const bf16x8 aq0 = *(const bf16x8*)(qrow + quad * 8);
  const bf16x8 aq1 = *(const bf16x8*)(qrow + 32 + quad * 8);

  const float k2m = __uint_as_float(k2maxu[bh * 16]);
  const float c1q = c1a[rowbase + qg];
  const float dvq = dva[rowbase + qg];
  const float Mqq = c1q * sqrtf(q2a[rowbase + qg] * k2m);
  float L = 0.0f;
  f32x4 O[4];
#pragma unroll
  for (int nt = 0; nt < 4; ++nt) O[nt] = (f32x4)(0.0f);

  const unsigned short* Kg = Ksw + (size_t)bh * 32 * 4096;
  const unsigned short* Vg = Vsw + (size_t)bh * 32 * 4096;
  const int sw = quad ^ (ln & 7);
  const int sw1 = (4 + quad) ^ (ln & 7);

  for (int kt = 0; kt < 16; ++kt) {
    {
      const size_t tb = (size_t)(half * 16 + kt) * 4096 + wl * 1024;
      async16(Kg + tb + lane * 8, Kt + wl * 1024);
      async16(Kg + tb + 512 + lane * 8, Kt + wl * 1024 + 512);
      async16(Vg + tb + lane * 8, Vt + wl * 1024);
      async16(Vg + tb + 512 + lane * 8, Vt + wl * 1024 + 512);
    }
    __syncthreads();

    // ---- S^T = K Q^T ----
    f32x4 s[4];
#pragma unroll
    for (int nt = 0; nt < 4; ++nt) {
      const unsigned short* kb = Kt + (nt * 16 + ln) * 64;
      const bf16x8 b0 = *(const bf16x8*)(kb + sw * 8);
      const bf16x8 b1 = *(const bf16x8*)(kb + sw1 * 8);
      f32x4 a = (f32x4)(0.0f);
      a = __builtin_amdgcn_mfma_f32_16x16x32_bf16(b0, aq0, a, 0, 0, 0);
      a = __builtin_amdgcn_mfma_f32_16x16x32_bf16(b1, aq1, a, 0, 0, 0);
      s[nt] = a;
    }

    // ---- softmax (scalar per lane) + packed P^T write ----
#pragma unroll
    for (int nt = 0; nt < 4; ++nt) {
      const f32x4 k2v = *(const f32x4*)&k2h[kt * 64 + nt * 16 + quad * 4];
      const float p0 = __builtin_amdgcn_exp2f(c1q * s[nt][0] - dvq * k2v[0] - Mqq);
      const float p1 = __builtin_amdgcn_exp2f(c1q * s[nt][1] - dvq * k2v[1] - Mqq);
      const float p2 = __builtin_amdgcn_exp2f(c1q * s[nt][2] - dvq * k2v[2] - Mqq);
      const float p3 = __builtin_amdgcn_exp2f(c1q * s[nt][3] - dvq * k2v[3] - Mqq);
      L += (p0 + p1) + (p2 + p3);
      union { __hip_bfloat162 h; unsigned int u; } c01, c23;
      c01.h = __float22bfloat162_rn(make_float2(p0, p1));
      c23.h = __float22bfloat162_rn(make_float2(p2, p3));
      uint2 pu; pu.x = c01.u; pu.y = c23.u;
      *(uint2*)&Ps[(wl * 16 + ln) * 72 + nt * 16 + quad * 4] = pu;
    }
    const unsigned short* pr = Ps + (wl * 16 + ln) * 72;
    const bf16x8 pa0 = *(const bf16x8*)(pr + quad * 8);
    const bf16x8 pa1 = *(const bf16x8*)(pr + 32 + quad * 8);

    // ---- O += P V ----
#pragma unroll
    for (int nt = 0; nt < 4; ++nt) {
      const unsigned short* vb = Vt + (nt * 16 + ln) * 64;
      const bf16x8 vb0 = *(const bf16x8*)(vb + sw * 8);
      const bf16x8 vb1 = *(const bf16x8*)(vb + sw1 * 8);
      O[nt] = __builtin_amdgcn_mfma_f32_16x16x32_bf16(pa0, vb0, O[nt], 0, 0, 0);
      O[nt] = __builtin_amdgcn_mfma_f32_16x16x32_bf16(pa1, vb1, O[nt], 0, 0, 0);
    }
    __syncthreads();
  }

  // ---- L: sum across quads (lane holds query wl*16+ln) ----
  L += __shfl_xor(L, 16, 64);
  L += __shfl_xor(L, 32, 64);

  // ---- stage partial O (fp32, aliases K/V) and L (aliases Ps) ----
  float* Ost = (float*)(smem + half * 16384);
  float* Lst = (float*)(smem + 32768 + half * 9216);
#pragma unroll
  for (int nt = 0; nt < 4; ++nt)
#pragma unroll
    for (int r = 0; r < 4; ++r)
      Ost[(wl * 16 + quad * 4 + r) * 64 + nt * 16 + ln] = O[nt][r];
  if (quad == 0) Lst[wl * 16 + ln] = L;
  __syncthreads();

  // ---- combine halves, normalize, write bf16 swizzled [B,N,DIM] ----
  const float* O0 = (const float*)smem;
  const float* O1 = (const float*)(smem + 16384);
  const float* L0 = (const float*)(smem + 32768);
  const float* L1 = (const float*)(smem + 32768 + 9216);
  const int q = t >> 3, c8 = (t & 7) * 8;
  const float inv = 1.0f / (L0[q] + L1[q]);
  const int base = q * 64 + c8;
  float4 a0 = *(const float4*)&O0[base];
  float4 a1 = *(const float4*)&O0[base + 4];
  const float4 b0 = *(const float4*)&O1[base];
  const float4 b1 = *(const float4*)&O1[base + 4];
  union { unsigned short us[8]; uint4 v; } ov;
  ov.us[0] = f2bf((a0.x + b0.x) * inv);
  ov.us[1] = f2bf((a0.y + b0.y) * inv);
  ov.us[2] = f2bf((a0.z + b0.z) * inv);
  ov.us[3] = f2bf((a0.w + b0.w) * inv);
  ov.us[4] = f2bf((a1.x + b1.x) * inv);
  ov.us[5] = f2bf((a1.y + b1.y) * inv);
  ov.us[6] = f2bf((a1.z + b1.z) * inv);
  ov.us[7] = f2bf((a1.w + b1.w) * inv);
  const int nrow = q0 + q;
  *(uint4*)&attnb[((size_t)(b * NNq + nrow)) * 512 + swzk(nrow, h * 64 + c8)] = ov.v;
}

// ---------------------------------------------------------------------------
// Staged out projection: out fp32 = attnb bf16 [4096,512] @ WoT + bo.
// BK=128, swizzle-aware reads, Tl aliased onto S. grid (64,8).
// ---------------------------------------------------------------------------
__global__ __launch_bounds__(256) void gemm_out(
    const unsigned short* __restrict__ A, const unsigned short* __restrict__ Wt,
    const float* __restrict__ bias, float* __restrict__ of) {
  __shared__ __align__(16) char sbuf[32768];  // As[64][128] | Bs[64][128]
  unsigned short* S = (unsigned short*)sbuf;
  float (*Tl)[68] = (float(*)[68])sbuf;  // aliased epilogue staging

  const int t = threadIdx.x;
  const int w = t >> 6, lane = t & 63, ln = lane & 15, quad = lane >> 4;
  const int r0 = blockIdx.x * 64, c0 = blockIdx.y * 64;
  const int lr = lane >> 4, lc = (lane & 15) * 8;

  f32x4 acc[4];
#pragma unroll
  for (int nt = 0; nt < 4; ++nt) acc[nt] = (f32x4)(0.0f);

  for (int k0 = 0; k0 < 512; k0 += 128) {
#pragma unroll
    for (int i = 0; i < 4; ++i) {
      async16(A + (size_t)(r0 + w * 16 + i * 4 + lr) * 512 + k0 + lc,
              S + (w * 16 + i * 4) * 128);
      async16(Wt + (size_t)(c0 + w * 16 + i * 4 + lr) * 512 + k0 + lc,
              S + 8192 + (w * 16 + i * 4) * 128);
    }
    __syncthreads();
#pragma unroll
    for (int kk = 0; kk < 128; kk += 32) {
      const int cp = (kk >> 3) + quad;
      const int cs = ((cp & 8) | ((cp ^ (ln & 7)) & 7)) * 8;
      const bf16x8 af = *(const bf16x8*)&S[(w * 16 + ln) * 128 + cs];
#pragma unroll
      for (int nt = 0; nt < 4; ++nt) {
        const bf16x8 bf = *(const bf16x8*)&S[8192 + (nt * 16 + ln) * 128 + cs];
        acc[nt] = __builtin_amdgcn_mfma_f32_16x16x32_bf16(af, bf, acc[nt], 0, 0, 0);
      }
    }
    __syncthreads();
  }
#pragma unroll
  for (int nt = 0; nt < 4; ++nt) {
    const float bv = bias[c0 + nt * 16 + ln];
#pragma unroll
    for (int r = 0; r < 4; ++r)
      Tl[w * 16 + quad * 4 + r][nt * 16 + ln] = acc[nt][r] + bv;
  }
  __syncthreads();
#pragma unroll
  for (int i = 0; i < 4; ++i) {
    const int idx = t + 256 * i;
    const int row = idx >> 4, c4 = (idx & 15) * 4;
    *(float4*)&of[(size_t)(r0 + row) * 512 + c0 + c4] = *(const float4*)&Tl[row][c4];
  }
}

// ---------------------------------------------------------------------------
extern "C" void kernel_launch(void* const* d_in, const int* in_sizes, int n_in,
                              void* d_out, int out_size, void* d_ws,
                              size_t ws_size, hipStream_t stream) {
  const float* z = (const float*)d_in[0];
  const float* Wq = (const float*)d_in[1];
  const float* bq = (const float*)d_in[2];
  const float* Wk = (const float*)d_in[3];
  const float* bk = (const float*)d_in[4];
  const float* Wv = (const float*)d_in[5];
  const float* bv = (const float*)d_in[6];
  const float* Wo = (const float*)d_in[7];
  const float* bo = (const float*)d_in[8];
  float* out = (float*)d_out;

  char* ws = (char*)d_ws;
  unsigned short* zb = (unsigned short*)(ws);                // 4 MiB
  unsigned short* Wt = (unsigned short*)(ws + 4194304);      // 2 MiB
  unsigned short* Qb = (unsigned short*)(ws + 6291456);      // 4 MiB
  unsigned short* Ksw = (unsigned short*)(ws + 10485760);    // 4 MiB
  unsigned short* Vsw = (unsigned short*)(ws + 14680064);    // 4 MiB
  float* c1 = (float*)(ws + 18874368);                       // 128 KiB each
  float* dv = (float*)(ws + 19005440);
  float* k2 = (float*)(ws + 19136512);
  float* q2 = (float*)(ws + 19267584);
  unsigned short* attnb = (unsigned short*)(ws + 19398656);  // 4 MiB
  unsigned int* k2max = (unsigned int*)(ws + 23592960);      // 1 KiB

  hipLaunchKernelGGL(prep_kernel, dim3(1281), dim3(256), 0, stream, z, Wq, Wk,
                     Wv, Wo, zb, Wt, k2max);
  hipLaunchKernelGGL(gemm_qkv, dim3(32, 8, 3), dim3(256), 0, stream, zb, Wt,
                     bq, bk, bv, Qb, Ksw, Vsw, c1, dv, k2, q2, k2max);
  hipLaunchKernelGGL(attn_kernel, dim3(32, 16), dim3(512), 0, stream, Qb, Ksw,
                     Vsw, c1, dv, k2, q2, k2max, attnb);
  hipLaunchKernelGGL(gemm_out, dim3(64, 8), dim3(256), 0, stream, attnb,
                     Wt + 786432, bo, out);
}